// Round 1
// baseline (170.842 us; speedup 1.0000x reference)
//
#include <hip/hip_runtime.h>
#include <hip/hip_bf16.h>

#define H 500
#define D_IN 512
#define D_OUT 100
#define STEPS 49
#define NWG 8

// ---------------- K1: xproj[t][r] = b_ih[r]+b_hh[r] + sum_d seq[t][d]*W_ih[r][d]
// seq[t][d] = x[d*49 + t]  (x is [1,512,7,7], t = i*7+j)
__global__ void k1_xproj(const float* __restrict__ x, const float* __restrict__ W_ih,
                         const float* __restrict__ b_ih, const float* __restrict__ b_hh,
                         float* __restrict__ xproj) {
    const int r = blockIdx.x;       // 0..499
    const int lane = threadIdx.x;   // 0..63
    float w[8];
#pragma unroll
    for (int k = 0; k < 8; k++) w[k] = W_ih[r * D_IN + k * 64 + lane];
    float p[STEPS];
#pragma unroll
    for (int t = 0; t < STEPS; t++) p[t] = 0.f;
#pragma unroll
    for (int k = 0; k < 8; k++) {
        const float* xr = x + (size_t)(k * 64 + lane) * STEPS;
#pragma unroll
        for (int t = 0; t < STEPS; t++) p[t] = fmaf(w[k], xr[t], p[t]);
    }
#pragma unroll
    for (int t = 0; t < STEPS; t++) {
        float v = p[t];
        v += __shfl_xor(v, 32); v += __shfl_xor(v, 16); v += __shfl_xor(v, 8);
        v += __shfl_xor(v, 4);  v += __shfl_xor(v, 2);  v += __shfl_xor(v, 1);
        p[t] = v;
    }
    if (lane == 0) {
        const float b = b_ih[r] + b_hh[r];
        for (int t = 0; t < STEPS; t++) xproj[t * H + r] = p[t] + b;
    }
}

// ---------------- K2: persistent cooperative scan over 49 steps.
// 8 WGs x 512 threads. WG g owns rows [g*64, g*64+64) (rows >= 500 inactive).
// thread tid -> (rl = tid>>3, q = tid&7); row = g*64+rl; cols chunk = [63q, 63q+63).
// Weights held in 63 registers per thread. h exchanged via global hbuf (double
// buffered) + per-WG monotone flags (release/acquire, agent scope).
__global__ __launch_bounds__(512, 1) void k2_scan(
    const float* __restrict__ hidden0, const float* __restrict__ W_hh,
    const float* __restrict__ xproj, float* hbuf, float* Hs, int* flags) {
    __shared__ float h_lds[512];
    const int g = blockIdx.x, tid = threadIdx.x;
    const int rl = tid >> 3, q = tid & 7;
    const int row = g * 64 + rl;
    const int cq = q * 63;

    float w[63];
#pragma unroll
    for (int i = 0; i < 63; i++) {
        const int c = cq + i;
        w[i] = (row < H && c < H) ? W_hh[row * H + c] : 0.f;
    }

    for (int t = 0; t < STEPS; t++) {
        if (t > 0) {
            if (tid < 64) {
                bool ok = (tid >= NWG);
                const int* fl = flags + tid * 64;
                while (!__all(ok)) {
                    if (!ok)
                        ok = (__hip_atomic_load(fl, __ATOMIC_ACQUIRE,
                                                __HIP_MEMORY_SCOPE_AGENT) >= t);
                }
            }
            __syncthreads();
        }
        // stage h_t into LDS
        if (tid < 504) {
            float v = 0.f;
            if (tid < H) {
                if (t == 0) v = hidden0[tid];
                else
                    v = __hip_atomic_load(hbuf + (t & 1) * 512 + tid,
                                          __ATOMIC_RELAXED, __HIP_MEMORY_SCOPE_AGENT);
            }
            h_lds[tid] = v;
        }
        __syncthreads();

        float acc = 0.f;
#pragma unroll
        for (int i = 0; i < 63; i++) acc = fmaf(w[i], h_lds[cq + i], acc);
        acc += __shfl_xor(acc, 1);
        acc += __shfl_xor(acc, 2);
        acc += __shfl_xor(acc, 4);

        if (q == 0 && row < H) {
            const float hv = tanhf(acc + xproj[t * H + row]);
            __hip_atomic_store(hbuf + ((t + 1) & 1) * 512 + row, hv,
                               __ATOMIC_RELAXED, __HIP_MEMORY_SCOPE_AGENT);
            Hs[t * 512 + row] = hv;
        }
        __syncthreads();
        if (tid == 0)
            __hip_atomic_store(flags + g * 64, t + 1, __ATOMIC_RELEASE,
                               __HIP_MEMORY_SCOPE_AGENT);
    }
}

// ---------------- K3: out[t][o] = tanh(b_out[o] + sum_c Hs[t][c]*W_out[o][c])
__global__ void k3_out(const float* __restrict__ Hs, const float* __restrict__ W_out,
                       const float* __restrict__ b_out, float* __restrict__ out) {
    const int t = blockIdx.x, o = threadIdx.x;
    if (o < D_OUT) {
        const float4* wr = (const float4*)(W_out + o * H);   // o*2000 B, 16B aligned
        const float4* hr = (const float4*)(Hs + t * 512);
        float acc = b_out[o];
#pragma unroll 5
        for (int i = 0; i < 125; i++) {
            const float4 wv = wr[i];
            const float4 hv = hr[i];
            acc = fmaf(wv.x, hv.x, acc);
            acc = fmaf(wv.y, hv.y, acc);
            acc = fmaf(wv.z, hv.z, acc);
            acc = fmaf(wv.w, hv.w, acc);
        }
        out[t * D_OUT + o] = tanhf(acc);
    }
}

extern "C" void kernel_launch(void* const* d_in, const int* in_sizes, int n_in,
                              void* d_out, int out_size, void* d_ws, size_t ws_size,
                              hipStream_t stream) {
    const float* x       = (const float*)d_in[0];
    const float* hidden0 = (const float*)d_in[1];
    const float* W_ih    = (const float*)d_in[2];
    const float* W_hh    = (const float*)d_in[3];
    const float* b_ih    = (const float*)d_in[4];
    const float* b_hh    = (const float*)d_in[5];
    const float* W_out   = (const float*)d_in[6];
    const float* b_out   = (const float*)d_in[7];
    float* out = (float*)d_out;

    char* ws = (char*)d_ws;
    int*   flags = (int*)ws;                                   // 8*64 ints = 2048 B
    float* xproj = (float*)(ws + 2048);                        // 49*500*4 = 98000 -> pad 98304
    float* Hs    = (float*)(ws + 2048 + 98304);                // 49*512*4 = 100352
    float* hbuf  = (float*)(ws + 2048 + 98304 + 100352);       // 2*512*4 = 4096

    hipMemsetAsync(flags, 0, 2048, stream);
    k1_xproj<<<H, 64, 0, stream>>>(x, W_ih, b_ih, b_hh, xproj);
    k2_scan<<<NWG, 512, 0, stream>>>(hidden0, W_hh, xproj, hbuf, Hs, flags);
    k3_out<<<STEPS, 128, 0, stream>>>(Hs, W_out, b_out, out);
}